// Round 1
// 597.347 us; speedup vs baseline: 1.0021x; 1.0021x over previous
//
#include <hip/hip_runtime.h>

// UpsamplingNearestSingle: N=262144 coarse voxels, C=64 ch, SCALE=2 -> 8 children.
// d_out (float32, concatenated): fine_data [N*8,64] then fine_ijk [N*8,3] as floats.
#define N_COARSE 262144
#define CHANNELS 64
#define DATA_F4     (N_COARSE * 8 * 16)   // 33554432 output float4s (fine_data)
#define DATA_BLOCKS 131072                // DATA_F4 / 256
#define IJK_ELEMS   (N_COARSE * 8 * 3)    // 6291456
#define IJK_BLOCKS  24576                 // IJK_ELEMS / 256

// Native clang vector type: __builtin_nontemporal_store needs a real vector,
// not HIP's float4 class. Same 16B layout -> global_store_dwordx4 nt.
typedef float nfloat4 __attribute__((ext_vector_type(4)));

// OUTPUT-DRIVEN data replication: thread j writes exactly out_data[j], so the
// store stream is perfectly sequential across the whole grid — identical shape
// to the 6.25 TB/s fillBuffer dispatch (vs the old input-driven 8-way 256B-stride
// NT fan-out that measured ~2.6 TB/s effective).
// Source index: fine row = j>>4, parent = fine_row>>3 = j>>7, c4 = j&15.
// All 8 redundant reads of one input float4 fall within 128 consecutive j =
// same block (2 waves) -> L1 broadcast serves 7/8; HBM read stays ~64 MB.
// Stores are nontemporal (pure streaming, never re-read); loads are cached.
__global__ void __launch_bounds__(256)
upsample_fused_kernel(const nfloat4* __restrict__ in, const int* __restrict__ ijk,
                      nfloat4* __restrict__ out_data, float* __restrict__ out_ijk) {
    const int b = blockIdx.x;
    if (b < DATA_BLOCKS) {
        const size_t j   = (size_t)b * 256 + threadIdx.x;   // output float4 index
        const size_t src = ((j >> 7) << 4) | (j & 15);      // parent*16 + c4
        __builtin_nontemporal_store(in[src], out_data + j);
    } else {
        const int e = (b - DATA_BLOCKS) * 256 + threadIdx.x;  // [0, IJK_ELEMS)
        const int r = e / 3;           // fine row (magic-mul)
        const int d = e - r * 3;       // dim 0..2
        const int n = r >> 3;          // parent voxel
        const int o = r & 7;           // child index
        const int off = (o >> (2 - d)) & 1;  // meshgrid ij-order offset bit
        __builtin_nontemporal_store((float)(ijk[n * 3 + d] * 2 + off), out_ijk + e);
    }
}

extern "C" void kernel_launch(void* const* d_in, const int* in_sizes, int n_in,
                              void* d_out, int out_size, void* d_ws, size_t ws_size,
                              hipStream_t stream) {
    const nfloat4* coarse_data = (const nfloat4*)d_in[0];
    const int*     coarse_ijk  = (const int*)d_in[1];

    float*   out      = (float*)d_out;
    nfloat4* out_data = (nfloat4*)out;
    float*   out_ijk  = out + (size_t)N_COARSE * 8 * CHANNELS;  // +134217728

    upsample_fused_kernel<<<DATA_BLOCKS + IJK_BLOCKS, 256, 0, stream>>>(
        coarse_data, coarse_ijk, out_data, out_ijk);
}